// Round 1
// baseline (703.694 us; speedup 1.0000x reference)
//
#include <hip/hip_runtime.h>
#include <hip/hip_bf16.h>

#define NN 50000
#define EE 800000
#define DIMM 128

typedef __attribute__((ext_vector_type(8))) short bf16x8;
typedef __attribute__((ext_vector_type(8))) unsigned short us8;
typedef __attribute__((ext_vector_type(4))) float f32x4;

static __device__ __forceinline__ unsigned short f2bf(float f) {
    unsigned int u = __float_as_uint(f);
    unsigned int r = (u + 0x7fffu + ((u >> 16) & 1u)) >> 16;
    return (unsigned short)r;
}

// ---------------- weight packing: W[K][N] fp32 -> Wt[N][K] bf16 ----------------
__global__ __launch_bounds__(256) void pack_w(
    const float* __restrict__ Wq, const float* __restrict__ Wk,
    const float* __restrict__ Wv, const float* __restrict__ Ws,
    const float* __restrict__ bq, const float* __restrict__ bk,
    const float* __restrict__ bv, const float* __restrict__ bs,
    const float* __restrict__ Wf1, const float* __restrict__ Wf2,
    unsigned short* __restrict__ wqkvsT, unsigned short* __restrict__ wf1T,
    unsigned short* __restrict__ wf2T, float* __restrict__ biasq)
{
    int i = blockIdx.x * 256 + threadIdx.x;
    if (i < 65536) {                       // wqkvsT[n][k], n in [0,512)
        int n = i >> 7, k = i & 127;
        int sel = n >> 7, col = n & 127;
        const float* W = sel == 0 ? Wq : sel == 1 ? Wk : sel == 2 ? Wv : Ws;
        wqkvsT[i] = f2bf(W[k * 128 + col]);
    } else if (i < 131072) {               // wf1T[n][k], n in [0,512), k in [0,128)
        int j = i - 65536; int n = j >> 7, k = j & 127;
        wf1T[j] = f2bf(Wf1[k * 512 + n]);
    } else if (i < 196608) {               // wf2T[n][k], n in [0,128), k in [0,512)
        int j = i - 131072; int n = j >> 9, k = j & 511;
        wf2T[j] = f2bf(Wf2[k * 128 + n]);
    } else if (i < 196608 + 512) {
        int j = i - 196608; int sel = j >> 7;
        const float* bp = sel == 0 ? bq : sel == 1 ? bk : sel == 2 ? bv : bs;
        biasq[j] = bp[j & 127];
    }
}

// ---------------- generic bf16 MFMA GEMM: C[M][Nn] = A[M][K] * Bt[Nn][K]^T + bias ----------------
// EPI 0: fp32 out + bias.  EPI 1: relu -> bf16 out + bias.
template<bool A_BF16, int EPI>
__global__ __launch_bounds__(256) void gemm_k(
    const void* __restrict__ Ap, const unsigned short* __restrict__ Bt,
    const float* __restrict__ bias, void* __restrict__ Cp,
    int M, int Nn, int K)
{
    __shared__ unsigned short As[128][72];   // 128 x 64 k, +8 pad
    __shared__ unsigned short Bs[64][72];
    int tid = threadIdx.x;
    int nb = Nn >> 6;                        // Nn / 64
    int bm = blockIdx.x / nb, bn = blockIdx.x % nb;
    int w = tid >> 6, lane = tid & 63;
    int wm = w >> 1, wn = w & 1;
    int lr = lane & 15, quad = lane >> 4;

    f32x4 acc[4][2];
    #pragma unroll
    for (int i = 0; i < 4; i++)
        #pragma unroll
        for (int j = 0; j < 2; j++) { f32x4 z = {0.f, 0.f, 0.f, 0.f}; acc[i][j] = z; }

    for (int kc = 0; kc < K; kc += 64) {
        // stage A tile (convert fp32->bf16 if needed)
        #pragma unroll
        for (int it = 0; it < 4; ++it) {
            int row = it * 32 + (tid >> 3);
            int k8 = (tid & 7) * 8;
            int rg = bm * 128 + row;
            us8 st = {0, 0, 0, 0, 0, 0, 0, 0};
            if (rg < M) {
                if constexpr (A_BF16) {
                    st = *(const us8*)((const unsigned short*)Ap + (size_t)rg * K + kc + k8);
                } else {
                    const float* src = (const float*)Ap + (size_t)rg * K + kc + k8;
                    float4 f0 = *(const float4*)src;
                    float4 f1 = *(const float4*)(src + 4);
                    st[0] = f2bf(f0.x); st[1] = f2bf(f0.y); st[2] = f2bf(f0.z); st[3] = f2bf(f0.w);
                    st[4] = f2bf(f1.x); st[5] = f2bf(f1.y); st[6] = f2bf(f1.z); st[7] = f2bf(f1.w);
                }
            }
            *(us8*)&As[row][k8] = st;
        }
        // stage B tile (already bf16, [n][k])
        {
            int nrow = tid >> 2;
            int k16 = (tid & 3) * 16;
            const unsigned short* src = Bt + (size_t)(bn * 64 + nrow) * K + kc + k16;
            *(us8*)&Bs[nrow][k16]     = *(const us8*)src;
            *(us8*)&Bs[nrow][k16 + 8] = *(const us8*)(src + 8);
        }
        __syncthreads();
        #pragma unroll
        for (int kk = 0; kk < 2; ++kk) {
            bf16x8 af[4], bfr[2];
            #pragma unroll
            for (int mi = 0; mi < 4; mi++)
                af[mi] = *(const bf16x8*)&As[wm * 64 + mi * 16 + lr][kk * 32 + quad * 8];
            #pragma unroll
            for (int ni = 0; ni < 2; ni++)
                bfr[ni] = *(const bf16x8*)&Bs[wn * 32 + ni * 16 + lr][kk * 32 + quad * 8];
            #pragma unroll
            for (int mi = 0; mi < 4; mi++)
                #pragma unroll
                for (int ni = 0; ni < 2; ni++)
                    acc[mi][ni] = __builtin_amdgcn_mfma_f32_16x16x32_bf16(af[mi], bfr[ni], acc[mi][ni], 0, 0, 0);
        }
        __syncthreads();
    }
    // epilogue: C/D layout col=lane&15, row=quad*4+r
    #pragma unroll
    for (int mi = 0; mi < 4; mi++) {
        #pragma unroll
        for (int ni = 0; ni < 2; ni++) {
            int cg = bn * 64 + wn * 32 + ni * 16 + lr;
            float bv = bias[cg];
            #pragma unroll
            for (int r = 0; r < 4; r++) {
                int rg = bm * 128 + wm * 64 + mi * 16 + quad * 4 + r;
                if (rg < M) {
                    float val = acc[mi][ni][r] + bv;
                    if constexpr (EPI == 1) {
                        val = fmaxf(val, 0.f);
                        ((unsigned short*)Cp)[(size_t)rg * Nn + cg] = f2bf(val);
                    } else {
                        ((float*)Cp)[(size_t)rg * Nn + cg] = val;
                    }
                }
            }
        }
    }
}

// ---------------- CSR build ----------------
__global__ __launch_bounds__(256) void hist_k(const int* __restrict__ dst, int* __restrict__ deg) {
    int e = blockIdx.x * 256 + threadIdx.x;
    if (e < EE) atomicAdd(&deg[dst[e]], 1);
}

__global__ __launch_bounds__(256) void scan_phaseA(const int* __restrict__ deg, int* __restrict__ rs,
                                                   int* __restrict__ bsum) {
    __shared__ int sm[256];
    int tid = threadIdx.x;
    int i = blockIdx.x * 256 + tid;
    int v = (i < NN) ? deg[i] : 0;
    sm[tid] = v;
    __syncthreads();
    #pragma unroll
    for (int off = 1; off < 256; off <<= 1) {
        int t = 0;
        if (tid >= off) t = sm[tid - off];
        __syncthreads();
        if (tid >= off) sm[tid] += t;
        __syncthreads();
    }
    if (i < NN) rs[i] = sm[tid] - v;              // block-local exclusive
    if (tid == 255) bsum[blockIdx.x] = sm[255];
}

__global__ __launch_bounds__(256) void scan_phaseB(int* __restrict__ bsum, int nb) {
    __shared__ int sm[256];
    int tid = threadIdx.x;
    int v = (tid < nb) ? bsum[tid] : 0;
    sm[tid] = v;
    __syncthreads();
    #pragma unroll
    for (int off = 1; off < 256; off <<= 1) {
        int t = 0;
        if (tid >= off) t = sm[tid - off];
        __syncthreads();
        if (tid >= off) sm[tid] += t;
        __syncthreads();
    }
    if (tid < nb) bsum[tid] = sm[tid] - v;        // exclusive
}

__global__ __launch_bounds__(256) void scan_phaseC(int* __restrict__ rs, const int* __restrict__ bsum) {
    int i = blockIdx.x * 256 + threadIdx.x;
    if (i < NN) rs[i] += bsum[blockIdx.x];
    if (i == 0) rs[NN] = EE;
}

__global__ __launch_bounds__(256) void scatter_k(const int* __restrict__ dst, const int* __restrict__ rs,
                                                 int* __restrict__ cur, int* __restrict__ eidx) {
    int e = blockIdx.x * 256 + threadIdx.x;
    if (e < EE) {
        int d = dst[e];
        int p = atomicAdd(&cur[d], 1);
        eidx[rs[d] + p] = e;
    }
}

// ---------------- fused attention (one wave per dst node) + beta gate + LN1 ----------------
__global__ __launch_bounds__(256, 4) void attn_kernel(
    const float* __restrict__ qkvs, const float* __restrict__ x,
    const float* __restrict__ eattr, const int* __restrict__ eindex,
    const int* __restrict__ rs, const int* __restrict__ eidx,
    const float* __restrict__ We, const float* __restrict__ be,
    const float* __restrict__ Wbeta, const float* __restrict__ gamma1,
    const float* __restrict__ beta1, float* __restrict__ hout)
{
    int wave = threadIdx.x >> 6;
    int lane = threadIdx.x & 63;
    int n = blockIdx.x * 4 + wave;
    if (n >= NN) return;
    int c0 = lane * 2, c1 = c0 + 1;

    // per-wave constants (uniform across nodes)
    float we0[16], we1[16];
    #pragma unroll
    for (int j = 0; j < 16; j++) { we0[j] = We[j * 128 + c0]; we1[j] = We[j * 128 + c1]; }
    float be0 = be[c0], be1 = be[c1];
    float wbo0 = Wbeta[c0],        wbo1 = Wbeta[c1];
    float wbx0 = Wbeta[128 + c0],  wbx1 = Wbeta[128 + c1];
    float wbd0 = Wbeta[256 + c0],  wbd1 = Wbeta[256 + c1];
    float gg0 = gamma1[c0], gg1 = gamma1[c1], bb0 = beta1[c0], bb1 = beta1[c1];

    const float* qrow = qkvs + (size_t)n * 512;
    float2 q2 = *(const float2*)(qrow + c0);
    float m = -__builtin_inff(), l = 0.f, a0 = 0.f, a1 = 0.f;

    int beg = rs[n], end = rs[n + 1];
    for (int ei = beg; ei < end; ++ei) {
        int e = eidx[ei];
        int s = eindex[e];                            // src node
        float eav = eattr[(size_t)e * 16 + (lane & 15)];
        float e0 = be0, e1 = be1;
        #pragma unroll
        for (int j = 0; j < 16; j++) {
            float aa = __shfl(eav, j);
            e0 = fmaf(aa, we0[j], e0);
            e1 = fmaf(aa, we1[j], e1);
        }
        const float* srow = qkvs + (size_t)s * 512;
        float2 k2 = *(const float2*)(srow + 128 + c0);
        float part = q2.x * (k2.x + e0) + q2.y * (k2.y + e1);
        part += __shfl_xor(part, 1);
        part += __shfl_xor(part, 2);
        part += __shfl_xor(part, 4);
        part += __shfl_xor(part, 8);
        float alpha = part * 0.17677669529663687f;    // 1/sqrt(32)
        float mn = fmaxf(m, alpha);
        float sc = __expf(m - mn);
        float p  = __expf(alpha - mn);
        l = l * sc + p;
        float2 v2 = *(const float2*)(srow + 256 + c0);
        a0 = a0 * sc + p * (v2.x + e0);
        a1 = a1 * sc + p * (v2.y + e1);
        m = mn;
    }
    float inv = l > 0.f ? 1.f / l : 0.f;
    float o0 = a0 * inv, o1 = a1 * inv;

    float2 xr2 = *(const float2*)(qrow + 384 + c0);
    float bl = o0 * wbo0 + o1 * wbo1 + xr2.x * wbx0 + xr2.y * wbx1
             + (o0 - xr2.x) * wbd0 + (o1 - xr2.y) * wbd1;
    #pragma unroll
    for (int off = 1; off < 64; off <<= 1) bl += __shfl_xor(bl, off);
    float beta = 1.f / (1.f + __expf(-bl));
    float xs0 = beta * xr2.x + (1.f - beta) * o0;
    float xs1 = beta * xr2.y + (1.f - beta) * o1;

    float2 xv = *(const float2*)(x + (size_t)n * 128 + c0);
    float t0 = xv.x + xs0, t1 = xv.y + xs1;
    float sm = t0 + t1;
    #pragma unroll
    for (int off = 1; off < 64; off <<= 1) sm += __shfl_xor(sm, off);
    float mu = sm * (1.f / 128.f);
    float d0 = t0 - mu, d1 = t1 - mu;
    float vv = d0 * d0 + d1 * d1;
    #pragma unroll
    for (int off = 1; off < 64; off <<= 1) vv += __shfl_xor(vv, off);
    float is = rsqrtf(vv * (1.f / 128.f) + 1e-5f);
    float h0 = d0 * is * gg0 + bb0;
    float h1 = d1 * is * gg1 + bb1;
    *(float2*)(hout + (size_t)n * 128 + c0) = make_float2(h0, h1);
}

// ---------------- final LN over h + ff2 ----------------
__global__ __launch_bounds__(256) void ln2_k(
    const float* __restrict__ h, const float* __restrict__ ff2,
    const float* __restrict__ gamma2, const float* __restrict__ beta2,
    float* __restrict__ out)
{
    int wave = threadIdx.x >> 6;
    int lane = threadIdx.x & 63;
    int n = blockIdx.x * 4 + wave;
    if (n >= NN) return;
    int c0 = lane * 2;
    float2 hv = *(const float2*)(h + (size_t)n * 128 + c0);
    float2 fv = *(const float2*)(ff2 + (size_t)n * 128 + c0);
    float t0 = hv.x + fv.x, t1 = hv.y + fv.y;
    float sm = t0 + t1;
    #pragma unroll
    for (int off = 1; off < 64; off <<= 1) sm += __shfl_xor(sm, off);
    float mu = sm * (1.f / 128.f);
    float d0 = t0 - mu, d1 = t1 - mu;
    float vv = d0 * d0 + d1 * d1;
    #pragma unroll
    for (int off = 1; off < 64; off <<= 1) vv += __shfl_xor(vv, off);
    float is = rsqrtf(vv * (1.f / 128.f) + 1e-5f);
    float o0 = d0 * is * gamma2[c0] + beta2[c0];
    float o1 = d1 * is * gamma2[c0 + 1] + beta2[c0 + 1];
    *(float2*)(out + (size_t)n * 128 + c0) = make_float2(o0, o1);
}

extern "C" void kernel_launch(void* const* d_in, const int* in_sizes, int n_in,
                              void* d_out, int out_size, void* d_ws, size_t ws_size,
                              hipStream_t stream) {
    const float* x      = (const float*)d_in[0];
    const int*   eindex = (const int*)d_in[1];     // [2][E]: src = [0..E), dst = [E..2E)
    const float* eattr  = (const float*)d_in[2];
    const float* Wq = (const float*)d_in[3];  const float* bq = (const float*)d_in[4];
    const float* Wk = (const float*)d_in[5];  const float* bk = (const float*)d_in[6];
    const float* Wv = (const float*)d_in[7];  const float* bv = (const float*)d_in[8];
    const float* We = (const float*)d_in[9];  const float* be = (const float*)d_in[10];
    const float* Ws = (const float*)d_in[11]; const float* bs = (const float*)d_in[12];
    const float* Wbeta = (const float*)d_in[13];
    const float* g1 = (const float*)d_in[14]; const float* b1 = (const float*)d_in[15];
    const float* Wf1 = (const float*)d_in[16]; const float* bf1 = (const float*)d_in[17];
    const float* Wf2 = (const float*)d_in[18]; const float* bf2 = (const float*)d_in[19];
    const float* g2 = (const float*)d_in[20]; const float* b2 = (const float*)d_in[21];

    char* ws = (char*)d_ws;
    size_t off = 0;
    unsigned short* wqkvsT = (unsigned short*)(ws + off); off += 512 * 128 * 2;        // 131072
    unsigned short* wf1T   = (unsigned short*)(ws + off); off += 512 * 128 * 2;
    unsigned short* wf2T   = (unsigned short*)(ws + off); off += 128 * 512 * 2;
    float* biasq           = (float*)(ws + off);          off += 512 * 4;
    float* qkvs            = (float*)(ws + off);          off += (size_t)NN * 512 * 4; // 102.4 MB
    float* h               = (float*)(ws + off);          off += (size_t)NN * 128 * 4; // 25.6 MB
    unsigned short* ff1    = (unsigned short*)(ws + off); off += (size_t)NN * 512 * 2; // 51.2 MB
    float* ff2             = (float*)(ws + off);          off += (size_t)NN * 128 * 4; // 25.6 MB
    int* deg               = (int*)(ws + off);            off += NN * 4;
    int* cursor            = (int*)(ws + off);            off += NN * 4;
    int* row_start         = (int*)(ws + off);            off += (NN + 1) * 4;
    int* bsum              = (int*)(ws + off);            off += 256 * 4;
    int* eidx              = (int*)(ws + off);            off += (size_t)EE * 4;

    // zero deg + cursor (adjacent)
    hipMemsetAsync(deg, 0, 2 * NN * 4, stream);

    pack_w<<<770, 256, 0, stream>>>(Wq, Wk, Wv, Ws, bq, bk, bv, bs, Wf1, Wf2,
                                    wqkvsT, wf1T, wf2T, biasq);

    // q|k|v|xr projections: [N,128] x [128,512]
    gemm_k<false, 0><<<391 * 8, 256, 0, stream>>>(x, wqkvsT, biasq, qkvs, NN, 512, 128);

    // CSR by dst
    hist_k<<<3125, 256, 0, stream>>>(eindex + EE, deg);
    scan_phaseA<<<196, 256, 0, stream>>>(deg, row_start, bsum);
    scan_phaseB<<<1, 256, 0, stream>>>(bsum, 196);
    scan_phaseC<<<196, 256, 0, stream>>>(row_start, bsum);
    scatter_k<<<3125, 256, 0, stream>>>(eindex + EE, row_start, cursor, eidx);

    // fused attention + beta gate + residual + LN1
    attn_kernel<<<12500, 256, 0, stream>>>(qkvs, x, eattr, eindex, row_start, eidx,
                                           We, be, Wbeta, g1, b1, h);

    // FFN
    gemm_k<false, 1><<<391 * 8, 256, 0, stream>>>(h, wf1T, bf1, ff1, NN, 512, 128);
    gemm_k<true, 0><<<391 * 2, 256, 0, stream>>>(ff1, wf2T, bf2, ff2, NN, 128, 512);

    // final LN
    ln2_k<<<12500, 256, 0, stream>>>(h, ff2, g2, b2, (float*)d_out);
}

// Round 2
// 581.263 us; speedup vs baseline: 1.2106x; 1.2106x over previous
//
#include <hip/hip_runtime.h>
#include <hip/hip_bf16.h>

#define NN 50000
#define EE 800000
#define DIMM 128

typedef __attribute__((ext_vector_type(8))) short bf16x8;
typedef __attribute__((ext_vector_type(8))) unsigned short us8;
typedef __attribute__((ext_vector_type(4))) float f32x4;

static __device__ __forceinline__ unsigned short f2bf(float f) {
    unsigned int u = __float_as_uint(f);
    unsigned int r = (u + 0x7fffu + ((u >> 16) & 1u)) >> 16;
    return (unsigned short)r;
}
static __device__ __forceinline__ float bf2f(unsigned short s) {
    return __uint_as_float(((unsigned int)s) << 16);
}

// ---------------- weight packing: W[K][N] fp32 -> Wt[N][K] bf16 ----------------
__global__ __launch_bounds__(256) void pack_w(
    const float* __restrict__ Wq, const float* __restrict__ Wk,
    const float* __restrict__ Wv, const float* __restrict__ Ws,
    const float* __restrict__ bq, const float* __restrict__ bk,
    const float* __restrict__ bv, const float* __restrict__ bs,
    const float* __restrict__ Wf1, const float* __restrict__ Wf2,
    unsigned short* __restrict__ wqkvsT, unsigned short* __restrict__ wf1T,
    unsigned short* __restrict__ wf2T, float* __restrict__ biasq)
{
    int i = blockIdx.x * 256 + threadIdx.x;
    if (i < 65536) {                       // wqkvsT[n][k], n in [0,512)
        int n = i >> 7, k = i & 127;
        int sel = n >> 7, col = n & 127;
        const float* W = sel == 0 ? Wq : sel == 1 ? Wk : sel == 2 ? Wv : Ws;
        wqkvsT[i] = f2bf(W[k * 128 + col]);
    } else if (i < 131072) {               // wf1T[n][k], n in [0,512), k in [0,128)
        int j = i - 65536; int n = j >> 7, k = j & 127;
        wf1T[j] = f2bf(Wf1[k * 512 + n]);
    } else if (i < 196608) {               // wf2T[n][k], n in [0,128), k in [0,512)
        int j = i - 131072; int n = j >> 9, k = j & 511;
        wf2T[j] = f2bf(Wf2[k * 128 + n]);
    } else if (i < 196608 + 512) {
        int j = i - 196608; int sel = j >> 7;
        const float* bp = sel == 0 ? bq : sel == 1 ? bk : sel == 2 ? bv : bs;
        biasq[j] = bp[j & 127];
    }
}

// ---------------- generic bf16 MFMA GEMM: C[M][Nn] = A[M][K] * Bt[Nn][K]^T + bias ----------------
// EPI 0: fp32 out + bias.  EPI 1: relu -> bf16 out + bias.  EPI 2: qkvs split (q fp32, kv bf16 interleaved, xr fp32)
template<bool A_BF16, int EPI>
__global__ __launch_bounds__(256) void gemm_k(
    const void* __restrict__ Ap, const unsigned short* __restrict__ Bt,
    const float* __restrict__ bias, void* __restrict__ Cp,
    float* __restrict__ qb, unsigned short* __restrict__ kvb, float* __restrict__ xrb,
    int M, int Nn, int K)
{
    __shared__ unsigned short As[128][72];   // 128 x 64 k, +8 pad
    __shared__ unsigned short Bs[64][72];
    int tid = threadIdx.x;
    int nb = Nn >> 6;                        // Nn / 64
    int bm = blockIdx.x / nb, bn = blockIdx.x % nb;
    int w = tid >> 6, lane = tid & 63;
    int wm = w >> 1, wn = w & 1;
    int lr = lane & 15, quad = lane >> 4;

    f32x4 acc[4][2];
    #pragma unroll
    for (int i = 0; i < 4; i++)
        #pragma unroll
        for (int j = 0; j < 2; j++) { f32x4 z = {0.f, 0.f, 0.f, 0.f}; acc[i][j] = z; }

    for (int kc = 0; kc < K; kc += 64) {
        #pragma unroll
        for (int it = 0; it < 4; ++it) {
            int row = it * 32 + (tid >> 3);
            int k8 = (tid & 7) * 8;
            int rg = bm * 128 + row;
            us8 st = {0, 0, 0, 0, 0, 0, 0, 0};
            if (rg < M) {
                if constexpr (A_BF16) {
                    st = *(const us8*)((const unsigned short*)Ap + (size_t)rg * K + kc + k8);
                } else {
                    const float* src = (const float*)Ap + (size_t)rg * K + kc + k8;
                    float4 f0 = *(const float4*)src;
                    float4 f1 = *(const float4*)(src + 4);
                    st[0] = f2bf(f0.x); st[1] = f2bf(f0.y); st[2] = f2bf(f0.z); st[3] = f2bf(f0.w);
                    st[4] = f2bf(f1.x); st[5] = f2bf(f1.y); st[6] = f2bf(f1.z); st[7] = f2bf(f1.w);
                }
            }
            *(us8*)&As[row][k8] = st;
        }
        {
            int nrow = tid >> 2;
            int k16 = (tid & 3) * 16;
            const unsigned short* src = Bt + (size_t)(bn * 64 + nrow) * K + kc + k16;
            *(us8*)&Bs[nrow][k16]     = *(const us8*)src;
            *(us8*)&Bs[nrow][k16 + 8] = *(const us8*)(src + 8);
        }
        __syncthreads();
        #pragma unroll
        for (int kk = 0; kk < 2; ++kk) {
            bf16x8 af[4], bfr[2];
            #pragma unroll
            for (int mi = 0; mi < 4; mi++)
                af[mi] = *(const bf16x8*)&As[wm * 64 + mi * 16 + lr][kk * 32 + quad * 8];
            #pragma unroll
            for (int ni = 0; ni < 2; ni++)
                bfr[ni] = *(const bf16x8*)&Bs[wn * 32 + ni * 16 + lr][kk * 32 + quad * 8];
            #pragma unroll
            for (int mi = 0; mi < 4; mi++)
                #pragma unroll
                for (int ni = 0; ni < 2; ni++)
                    acc[mi][ni] = __builtin_amdgcn_mfma_f32_16x16x32_bf16(af[mi], bfr[ni], acc[mi][ni], 0, 0, 0);
        }
        __syncthreads();
    }
    #pragma unroll
    for (int mi = 0; mi < 4; mi++) {
        #pragma unroll
        for (int ni = 0; ni < 2; ni++) {
            int cg = bn * 64 + wn * 32 + ni * 16 + lr;
            float bv = bias[cg];
            #pragma unroll
            for (int r = 0; r < 4; r++) {
                int rg = bm * 128 + wm * 64 + mi * 16 + quad * 4 + r;
                if (rg < M) {
                    float val = acc[mi][ni][r] + bv;
                    if constexpr (EPI == 0) {
                        ((float*)Cp)[(size_t)rg * Nn + cg] = val;
                    } else if constexpr (EPI == 1) {
                        val = fmaxf(val, 0.f);
                        ((unsigned short*)Cp)[(size_t)rg * Nn + cg] = f2bf(val);
                    } else {
                        int sel = cg >> 7, c = cg & 127;
                        if (sel == 0)      qb[(size_t)rg * 128 + c] = val;
                        else if (sel == 1) kvb[(size_t)rg * 256 + 2 * c] = f2bf(val);
                        else if (sel == 2) kvb[(size_t)rg * 256 + 2 * c + 1] = f2bf(val);
                        else               xrb[(size_t)rg * 128 + c] = val;
                    }
                }
            }
        }
    }
}

// ---------------- CSR build ----------------
__global__ __launch_bounds__(256) void hist_k(const int* __restrict__ dst, int* __restrict__ deg) {
    int e = blockIdx.x * 256 + threadIdx.x;
    if (e < EE) atomicAdd(&deg[dst[e]], 1);
}

__global__ __launch_bounds__(256) void scan_phaseA(const int* __restrict__ deg, int* __restrict__ rs,
                                                   int* __restrict__ bsum) {
    __shared__ int sm[256];
    int tid = threadIdx.x;
    int i = blockIdx.x * 256 + tid;
    int v = (i < NN) ? deg[i] : 0;
    sm[tid] = v;
    __syncthreads();
    #pragma unroll
    for (int off = 1; off < 256; off <<= 1) {
        int t = 0;
        if (tid >= off) t = sm[tid - off];
        __syncthreads();
        if (tid >= off) sm[tid] += t;
        __syncthreads();
    }
    if (i < NN) rs[i] = sm[tid] - v;
    if (tid == 255) bsum[blockIdx.x] = sm[255];
}

__global__ __launch_bounds__(256) void scan_phaseB(int* __restrict__ bsum, int nb) {
    __shared__ int sm[256];
    int tid = threadIdx.x;
    int v = (tid < nb) ? bsum[tid] : 0;
    sm[tid] = v;
    __syncthreads();
    #pragma unroll
    for (int off = 1; off < 256; off <<= 1) {
        int t = 0;
        if (tid >= off) t = sm[tid - off];
        __syncthreads();
        if (tid >= off) sm[tid] += t;
        __syncthreads();
    }
    if (tid < nb) bsum[tid] = sm[tid] - v;
}

__global__ __launch_bounds__(256) void scan_phaseC(int* __restrict__ rs, const int* __restrict__ bsum) {
    int i = blockIdx.x * 256 + threadIdx.x;
    if (i < NN) rs[i] += bsum[blockIdx.x];
    if (i == 0) rs[NN] = EE;
}

// scatter: build srcs_sorted + bf16-permuted eattr_sorted
__global__ __launch_bounds__(256) void scatter_k(
    const int* __restrict__ src, const int* __restrict__ dst,
    const float* __restrict__ eattr, const int* __restrict__ rs,
    int* __restrict__ cur, int* __restrict__ srcs_sorted,
    unsigned short* __restrict__ eas)
{
    int e = blockIdx.x * 256 + threadIdx.x;
    if (e < EE) {
        int d = dst[e];
        int p = atomicAdd(&cur[d], 1);
        int pos = rs[d] + p;
        srcs_sorted[pos] = src[e];
        const float* ap = eattr + (size_t)e * 16;
        float4 a0 = *(const float4*)ap;
        float4 a1 = *(const float4*)(ap + 4);
        float4 a2 = *(const float4*)(ap + 8);
        float4 a3 = *(const float4*)(ap + 12);
        us8 lo, hi;
        lo[0] = f2bf(a0.x); lo[1] = f2bf(a0.y); lo[2] = f2bf(a0.z); lo[3] = f2bf(a0.w);
        lo[4] = f2bf(a1.x); lo[5] = f2bf(a1.y); lo[6] = f2bf(a1.z); lo[7] = f2bf(a1.w);
        hi[0] = f2bf(a2.x); hi[1] = f2bf(a2.y); hi[2] = f2bf(a2.z); hi[3] = f2bf(a2.w);
        hi[4] = f2bf(a3.x); hi[5] = f2bf(a3.y); hi[6] = f2bf(a3.z); hi[7] = f2bf(a3.w);
        *(us8*)(eas + (size_t)pos * 16)     = lo;
        *(us8*)(eas + (size_t)pos * 16 + 8) = hi;
    }
}

// ---------------- fused attention (one wave per dst node) + beta gate + LN1 ----------------
// No max-subtraction: alpha ~ N(0,~1.4), exp() safe in fp32. Sum is reorderable ->
// process edges in groups of 4 with all gathers in flight; prefetch next group.
__global__ __launch_bounds__(256, 3) void attn_kernel(
    const float* __restrict__ q, const unsigned int* __restrict__ kvb,
    const float* __restrict__ xr, const float* __restrict__ x,
    const unsigned short* __restrict__ eas, const int* __restrict__ srcs,
    const int* __restrict__ rs,
    const float* __restrict__ We, const float* __restrict__ be,
    const float* __restrict__ Wbeta, const float* __restrict__ gamma1,
    const float* __restrict__ beta1, float* __restrict__ hout)
{
    int wave = threadIdx.x >> 6;
    int lane = threadIdx.x & 63;
    int n = blockIdx.x * 4 + wave;
    if (n >= NN) return;
    int c0 = lane * 2, c1 = c0 + 1;

    float we0[16], we1[16];
    #pragma unroll
    for (int j = 0; j < 16; j++) { we0[j] = We[j * 128 + c0]; we1[j] = We[j * 128 + c1]; }
    float be0 = be[c0], be1 = be[c1];

    float2 q2 = *(const float2*)(q + (size_t)n * 128 + c0);
    q2.x *= 0.17677669529663687f;   // 1/sqrt(32) folded into q
    q2.y *= 0.17677669529663687f;

    float l = 0.f, a0 = 0.f, a1 = 0.f;
    int beg = rs[n], end = rs[n + 1];

    const size_t EAS_MAX = (size_t)EE * 16 - 1;
    // prologue: load group 0
    float ea_c = bf2f(eas[min((size_t)beg * 16 + lane, EAS_MAX)]);
    int sr_c[4];
    #pragma unroll
    for (int j = 0; j < 4; j++) sr_c[j] = srcs[min(beg + j, EE - 1)];

    for (int g = beg; g < end; g += 4) {
        int cnt = end - g;
        // current group's kv gathers (one uint2 = k0,v0,k1,v1 bf16 per lane)
        uint2 kvp[4];
        #pragma unroll
        for (int j = 0; j < 4; j++)
            kvp[j] = *(const uint2*)(kvb + (size_t)sr_c[j] * 128 + (lane << 1));
        // prefetch next group (clamped; values unused past end)
        int gn = g + 4;
        float ea_n = bf2f(eas[min((size_t)gn * 16 + lane, EAS_MAX)]);
        int sr_n[4];
        #pragma unroll
        for (int j = 0; j < 4; j++) sr_n[j] = srcs[min(gn + j, EE - 1)];

        #pragma unroll
        for (int j = 0; j < 4; j++) {
            if (j < cnt) {
                float e0 = be0, e1 = be1;
                #pragma unroll
                for (int t = 0; t < 16; t++) {
                    float aa = __shfl(ea_c, j * 16 + t);
                    e0 = fmaf(aa, we0[t], e0);
                    e1 = fmaf(aa, we1[t], e1);
                }
                unsigned int kx = kvp[j].x, ky = kvp[j].y;
                float k0 = __uint_as_float(kx << 16);
                float v0 = __uint_as_float(kx & 0xffff0000u);
                float k1 = __uint_as_float(ky << 16);
                float v1 = __uint_as_float(ky & 0xffff0000u);
                float part = q2.x * (k0 + e0) + q2.y * (k1 + e1);
                part += __shfl_xor(part, 1);
                part += __shfl_xor(part, 2);
                part += __shfl_xor(part, 4);
                part += __shfl_xor(part, 8);
                float wgt = __expf(part);
                l += wgt;
                a0 = fmaf(wgt, v0 + e0, a0);
                a1 = fmaf(wgt, v1 + e1, a1);
            }
        }
        ea_c = ea_n;
        #pragma unroll
        for (int j = 0; j < 4; j++) sr_c[j] = sr_n[j];
    }

    float inv = l > 0.f ? 1.f / l : 0.f;
    float o0 = a0 * inv, o1 = a1 * inv;

    // beta gate (loads here to keep loop registers light)
    float wbo0 = Wbeta[c0],        wbo1 = Wbeta[c1];
    float wbx0 = Wbeta[128 + c0],  wbx1 = Wbeta[128 + c1];
    float wbd0 = Wbeta[256 + c0],  wbd1 = Wbeta[256 + c1];
    float2 xr2 = *(const float2*)(xr + (size_t)n * 128 + c0);
    float bl = o0 * wbo0 + o1 * wbo1 + xr2.x * wbx0 + xr2.y * wbx1
             + (o0 - xr2.x) * wbd0 + (o1 - xr2.y) * wbd1;
    #pragma unroll
    for (int off = 1; off < 64; off <<= 1) bl += __shfl_xor(bl, off);
    float beta = 1.f / (1.f + __expf(-bl));
    float xs0 = beta * xr2.x + (1.f - beta) * o0;
    float xs1 = beta * xr2.y + (1.f - beta) * o1;

    float2 xv = *(const float2*)(x + (size_t)n * 128 + c0);
    float t0 = xv.x + xs0, t1 = xv.y + xs1;
    float sm = t0 + t1;
    #pragma unroll
    for (int off = 1; off < 64; off <<= 1) sm += __shfl_xor(sm, off);
    float mu = sm * (1.f / 128.f);
    float d0 = t0 - mu, d1 = t1 - mu;
    float vv = d0 * d0 + d1 * d1;
    #pragma unroll
    for (int off = 1; off < 64; off <<= 1) vv += __shfl_xor(vv, off);
    float is = rsqrtf(vv * (1.f / 128.f) + 1e-5f);
    float h0 = d0 * is * gamma1[c0] + beta1[c0];
    float h1 = d1 * is * gamma1[c1] + beta1[c1];
    *(float2*)(hout + (size_t)n * 128 + c0) = make_float2(h0, h1);
}

// ---------------- final LN over h + ff2 ----------------
__global__ __launch_bounds__(256) void ln2_k(
    const float* __restrict__ h, const float* __restrict__ ff2,
    const float* __restrict__ gamma2, const float* __restrict__ beta2,
    float* __restrict__ out)
{
    int wave = threadIdx.x >> 6;
    int lane = threadIdx.x & 63;
    int n = blockIdx.x * 4 + wave;
    if (n >= NN) return;
    int c0 = lane * 2;
    float2 hv = *(const float2*)(h + (size_t)n * 128 + c0);
    float2 fv = *(const float2*)(ff2 + (size_t)n * 128 + c0);
    float t0 = hv.x + fv.x, t1 = hv.y + fv.y;
    float sm = t0 + t1;
    #pragma unroll
    for (int off = 1; off < 64; off <<= 1) sm += __shfl_xor(sm, off);
    float mu = sm * (1.f / 128.f);
    float d0 = t0 - mu, d1 = t1 - mu;
    float vv = d0 * d0 + d1 * d1;
    #pragma unroll
    for (int off = 1; off < 64; off <<= 1) vv += __shfl_xor(vv, off);
    float is = rsqrtf(vv * (1.f / 128.f) + 1e-5f);
    float o0 = d0 * is * gamma2[c0] + beta2[c0];
    float o1 = d1 * is * gamma2[c0 + 1] + beta2[c0 + 1];
    *(float2*)(out + (size_t)n * 128 + c0) = make_float2(o0, o1);
}

extern "C" void kernel_launch(void* const* d_in, const int* in_sizes, int n_in,
                              void* d_out, int out_size, void* d_ws, size_t ws_size,
                              hipStream_t stream) {
    const float* x      = (const float*)d_in[0];
    const int*   eindex = (const int*)d_in[1];     // [2][E]: src = [0..E), dst = [E..2E)
    const float* eattr  = (const float*)d_in[2];
    const float* Wq = (const float*)d_in[3];  const float* bq = (const float*)d_in[4];
    const float* Wk = (const float*)d_in[5];  const float* bk = (const float*)d_in[6];
    const float* Wv = (const float*)d_in[7];  const float* bv = (const float*)d_in[8];
    const float* We = (const float*)d_in[9];  const float* be = (const float*)d_in[10];
    const float* Ws = (const float*)d_in[11]; const float* bs = (const float*)d_in[12];
    const float* Wbeta = (const float*)d_in[13];
    const float* g1 = (const float*)d_in[14]; const float* b1 = (const float*)d_in[15];
    const float* Wf1 = (const float*)d_in[16]; const float* bf1 = (const float*)d_in[17];
    const float* Wf2 = (const float*)d_in[18]; const float* bf2 = (const float*)d_in[19];
    const float* g2 = (const float*)d_in[20]; const float* b2 = (const float*)d_in[21];

    char* ws = (char*)d_ws;
    size_t off = 0;
    unsigned short* wqkvsT = (unsigned short*)(ws + off); off += 512 * 128 * 2;
    unsigned short* wf1T   = (unsigned short*)(ws + off); off += 512 * 128 * 2;
    unsigned short* wf2T   = (unsigned short*)(ws + off); off += 128 * 512 * 2;
    float* biasq           = (float*)(ws + off);          off += 512 * 4;
    float* qb              = (float*)(ws + off);          off += (size_t)NN * 128 * 4; // 25.6 MB
    unsigned short* kvb    = (unsigned short*)(ws + off); off += (size_t)NN * 256 * 2; // 25.6 MB
    float* xrb             = (float*)(ws + off);          off += (size_t)NN * 128 * 4; // 25.6 MB
    float* h               = (float*)(ws + off);          off += (size_t)NN * 128 * 4; // 25.6 MB
    unsigned short* ff1    = (unsigned short*)(ws + off); off += (size_t)NN * 512 * 2; // 51.2 MB
    float* ff2             = (float*)(ws + off);          off += (size_t)NN * 128 * 4; // 25.6 MB
    int* deg               = (int*)(ws + off);            off += NN * 4;
    int* cursor            = (int*)(ws + off);            off += NN * 4;
    int* row_start         = (int*)(ws + off);            off += (NN + 1) * 4;
    int* bsum              = (int*)(ws + off);            off += 256 * 4;
    int* srcs_sorted       = (int*)(ws + off);            off += (size_t)EE * 4;       // 3.2 MB
    unsigned short* eas    = (unsigned short*)(ws + off); off += (size_t)EE * 16 * 2;  // 25.6 MB

    hipMemsetAsync(deg, 0, 2 * NN * 4, stream);   // deg + cursor

    pack_w<<<770, 256, 0, stream>>>(Wq, Wk, Wv, Ws, bq, bk, bv, bs, Wf1, Wf2,
                                    wqkvsT, wf1T, wf2T, biasq);

    // q|k|v|xr projections with split epilogue
    gemm_k<false, 2><<<391 * 8, 256, 0, stream>>>(x, wqkvsT, biasq, nullptr,
                                                  qb, kvb, xrb, NN, 512, 128);

    // CSR by dst + permuted src/eattr
    hist_k<<<3125, 256, 0, stream>>>(eindex + EE, deg);
    scan_phaseA<<<196, 256, 0, stream>>>(deg, row_start, bsum);
    scan_phaseB<<<1, 256, 0, stream>>>(bsum, 196);
    scan_phaseC<<<196, 256, 0, stream>>>(row_start, bsum);
    scatter_k<<<3125, 256, 0, stream>>>(eindex, eindex + EE, eattr, row_start,
                                        cursor, srcs_sorted, eas);

    // fused attention + beta gate + residual + LN1
    attn_kernel<<<12500, 256, 0, stream>>>(qb, (const unsigned int*)kvb, xrb, x,
                                           eas, srcs_sorted, row_start,
                                           We, be, Wbeta, g1, b1, h);

    // FFN
    gemm_k<false, 1><<<391 * 8, 256, 0, stream>>>(h, wf1T, bf1, ff1,
                                                  nullptr, nullptr, nullptr, NN, 512, 128);
    gemm_k<true, 0><<<391 * 2, 256, 0, stream>>>(ff1, wf2T, bf2, ff2,
                                                 nullptr, nullptr, nullptr, NN, 128, 512);

    // final LN
    ln2_k<<<12500, 256, 0, stream>>>(h, ff2, g2, b2, (float*)d_out);
}

// Round 5
// 527.010 us; speedup vs baseline: 1.3353x; 1.1029x over previous
//
#include <hip/hip_runtime.h>
#include <hip/hip_bf16.h>

#define NN 50000
#define EE 800000
#define DIMM 128

typedef __attribute__((ext_vector_type(8))) short bf16x8;
typedef __attribute__((ext_vector_type(8))) unsigned short us8;
typedef __attribute__((ext_vector_type(4))) float f32x4;

static __device__ __forceinline__ unsigned short f2bf(float f) {
    unsigned int u = __float_as_uint(f);
    unsigned int r = (u + 0x7fffu + ((u >> 16) & 1u)) >> 16;
    return (unsigned short)r;
}
static __device__ __forceinline__ float bf2f(unsigned short s) {
    return __uint_as_float(((unsigned int)s) << 16);
}

// ---------------- weight packing ----------------
__global__ __launch_bounds__(256) void pack_w(
    const float* __restrict__ Wq, const float* __restrict__ Wk,
    const float* __restrict__ Wv, const float* __restrict__ Ws,
    const float* __restrict__ bq, const float* __restrict__ bk,
    const float* __restrict__ bv, const float* __restrict__ bs,
    const float* __restrict__ Wf1, const float* __restrict__ Wf2,
    unsigned short* __restrict__ wqkvsT, unsigned short* __restrict__ wf1T,
    unsigned short* __restrict__ wf2T, float* __restrict__ biasq)
{
    int i = blockIdx.x * 256 + threadIdx.x;
    if (i < 65536) {                       // wqkvsT[n][k], n in [0,512)
        int n = i >> 7, k = i & 127;
        int sel = n >> 7, col = n & 127;
        const float* W = sel == 0 ? Wq : sel == 1 ? Wk : sel == 2 ? Wv : Ws;
        wqkvsT[i] = f2bf(W[k * 128 + col]);
    } else if (i < 131072) {               // wf1T[n][k]
        int j = i - 65536; int n = j >> 7, k = j & 127;
        wf1T[j] = f2bf(Wf1[k * 512 + n]);
    } else if (i < 196608) {               // wf2T[n][k]
        int j = i - 131072; int n = j >> 9, k = j & 511;
        wf2T[j] = f2bf(Wf2[k * 128 + n]);
    } else if (i < 197120) {
        int j = i - 196608; int sel = j >> 7;
        const float* bp = sel == 0 ? bq : sel == 1 ? bk : sel == 2 ? bv : bs;
        biasq[j] = bp[j & 127];
    }
}

// ---------------- generic bf16 MFMA GEMM ----------------
// EPI 0: fp32 out + bias.  EPI 1: relu -> bf16 out + bias.  EPI 2: qkvs split.
template<bool A_BF16, int EPI>
__global__ __launch_bounds__(256) void gemm_k(
    const void* __restrict__ Ap, const unsigned short* __restrict__ Bt,
    const float* __restrict__ bias, void* __restrict__ Cp,
    float* __restrict__ qb, unsigned short* __restrict__ kvb, float* __restrict__ xrb,
    int M, int Nn, int K)
{
    __shared__ unsigned short As[128][72];
    __shared__ unsigned short Bs[64][72];
    int tid = threadIdx.x;
    int nb = Nn >> 6;
    int bm = blockIdx.x / nb, bn = blockIdx.x % nb;
    int w = tid >> 6, lane = tid & 63;
    int wm = w >> 1, wn = w & 1;
    int lr = lane & 15, quad = lane >> 4;

    f32x4 acc[4][2];
    #pragma unroll
    for (int i = 0; i < 4; i++)
        #pragma unroll
        for (int j = 0; j < 2; j++) { f32x4 z = {0.f, 0.f, 0.f, 0.f}; acc[i][j] = z; }

    for (int kc = 0; kc < K; kc += 64) {
        #pragma unroll
        for (int it = 0; it < 4; ++it) {
            int row = it * 32 + (tid >> 3);
            int k8 = (tid & 7) * 8;
            int rg = bm * 128 + row;
            us8 st = {0, 0, 0, 0, 0, 0, 0, 0};
            if (rg < M) {
                if constexpr (A_BF16) {
                    st = *(const us8*)((const unsigned short*)Ap + (size_t)rg * K + kc + k8);
                } else {
                    const float* src = (const float*)Ap + (size_t)rg * K + kc + k8;
                    float4 f0 = *(const float4*)src;
                    float4 f1 = *(const float4*)(src + 4);
                    st[0] = f2bf(f0.x); st[1] = f2bf(f0.y); st[2] = f2bf(f0.z); st[3] = f2bf(f0.w);
                    st[4] = f2bf(f1.x); st[5] = f2bf(f1.y); st[6] = f2bf(f1.z); st[7] = f2bf(f1.w);
                }
            }
            *(us8*)&As[row][k8] = st;
        }
        {
            int nrow = tid >> 2;
            int k16 = (tid & 3) * 16;
            const unsigned short* src = Bt + (size_t)(bn * 64 + nrow) * K + kc + k16;
            *(us8*)&Bs[nrow][k16]     = *(const us8*)src;
            *(us8*)&Bs[nrow][k16 + 8] = *(const us8*)(src + 8);
        }
        __syncthreads();
        #pragma unroll
        for (int kk = 0; kk < 2; ++kk) {
            bf16x8 af[4], bfr[2];
            #pragma unroll
            for (int mi = 0; mi < 4; mi++)
                af[mi] = *(const bf16x8*)&As[wm * 64 + mi * 16 + lr][kk * 32 + quad * 8];
            #pragma unroll
            for (int ni = 0; ni < 2; ni++)
                bfr[ni] = *(const bf16x8*)&Bs[wn * 32 + ni * 16 + lr][kk * 32 + quad * 8];
            #pragma unroll
            for (int mi = 0; mi < 4; mi++)
                #pragma unroll
                for (int ni = 0; ni < 2; ni++)
                    acc[mi][ni] = __builtin_amdgcn_mfma_f32_16x16x32_bf16(af[mi], bfr[ni], acc[mi][ni], 0, 0, 0);
        }
        __syncthreads();
    }
    #pragma unroll
    for (int mi = 0; mi < 4; mi++) {
        #pragma unroll
        for (int ni = 0; ni < 2; ni++) {
            int cg = bn * 64 + wn * 32 + ni * 16 + lr;
            float bv = bias[cg];
            #pragma unroll
            for (int r = 0; r < 4; r++) {
                int rg = bm * 128 + wm * 64 + mi * 16 + quad * 4 + r;
                if (rg < M) {
                    float val = acc[mi][ni][r] + bv;
                    if constexpr (EPI == 0) {
                        ((float*)Cp)[(size_t)rg * Nn + cg] = val;
                    } else if constexpr (EPI == 1) {
                        val = fmaxf(val, 0.f);
                        ((unsigned short*)Cp)[(size_t)rg * Nn + cg] = f2bf(val);
                    } else {
                        int sel = cg >> 7, c = cg & 127;
                        if (sel == 0)      qb[(size_t)rg * 128 + c] = val;
                        else if (sel == 1) kvb[(size_t)rg * 256 + 2 * c] = f2bf(val);
                        else if (sel == 2) kvb[(size_t)rg * 256 + 2 * c + 1] = f2bf(val);
                        else               xrb[(size_t)rg * 128 + c] = val;
                    }
                }
            }
        }
    }
}

// ---------------- CSR build ----------------
__global__ __launch_bounds__(256) void hist_k(const int* __restrict__ dst, int* __restrict__ deg) {
    int e = blockIdx.x * 256 + threadIdx.x;
    if (e < EE) atomicAdd(&deg[dst[e]], 1);
}

__global__ __launch_bounds__(256) void scan_phaseA(const int* __restrict__ deg, int* __restrict__ rs,
                                                   int* __restrict__ bsum) {
    __shared__ int sm[256];
    int tid = threadIdx.x;
    int i = blockIdx.x * 256 + tid;
    int v = (i < NN) ? deg[i] : 0;
    sm[tid] = v;
    __syncthreads();
    #pragma unroll
    for (int off = 1; off < 256; off <<= 1) {
        int t = 0;
        if (tid >= off) t = sm[tid - off];
        __syncthreads();
        if (tid >= off) sm[tid] += t;
        __syncthreads();
    }
    if (i < NN) rs[i] = sm[tid] - v;
    if (tid == 255) bsum[blockIdx.x] = sm[255];
}

__global__ __launch_bounds__(256) void scan_phaseB(int* __restrict__ bsum, int nb) {
    __shared__ int sm[256];
    int tid = threadIdx.x;
    int v = (tid < nb) ? bsum[tid] : 0;
    sm[tid] = v;
    __syncthreads();
    #pragma unroll
    for (int off = 1; off < 256; off <<= 1) {
        int t = 0;
        if (tid >= off) t = sm[tid - off];
        __syncthreads();
        if (tid >= off) sm[tid] += t;
        __syncthreads();
    }
    if (tid < nb) bsum[tid] = sm[tid] - v;
}

__global__ __launch_bounds__(256) void scan_phaseC(int* __restrict__ rs, const int* __restrict__ bsum) {
    int i = blockIdx.x * 256 + threadIdx.x;
    if (i < NN) rs[i] += bsum[blockIdx.x];
    if (i == 0) rs[NN] = EE;
}

__global__ __launch_bounds__(256) void scatter_k(
    const int* __restrict__ src, const int* __restrict__ dst,
    const float* __restrict__ eattr, const int* __restrict__ rs,
    int* __restrict__ cur, int* __restrict__ srcs_sorted,
    unsigned short* __restrict__ eas)
{
    int e = blockIdx.x * 256 + threadIdx.x;
    if (e < EE) {
        int d = dst[e];
        int p = atomicAdd(&cur[d], 1);
        int pos = rs[d] + p;
        srcs_sorted[pos] = src[e];
        const float* ap = eattr + (size_t)e * 16;
        float4 a0 = *(const float4*)ap;
        float4 a1 = *(const float4*)(ap + 4);
        float4 a2 = *(const float4*)(ap + 8);
        float4 a3 = *(const float4*)(ap + 12);
        us8 lo, hi;
        lo[0] = f2bf(a0.x); lo[1] = f2bf(a0.y); lo[2] = f2bf(a0.z); lo[3] = f2bf(a0.w);
        lo[4] = f2bf(a1.x); lo[5] = f2bf(a1.y); lo[6] = f2bf(a1.z); lo[7] = f2bf(a1.w);
        hi[0] = f2bf(a2.x); hi[1] = f2bf(a2.y); hi[2] = f2bf(a2.z); hi[3] = f2bf(a2.w);
        hi[4] = f2bf(a3.x); hi[5] = f2bf(a3.y); hi[6] = f2bf(a3.z); hi[7] = f2bf(a3.w);
        *(us8*)(eas + (size_t)pos * 16)     = lo;
        *(us8*)(eas + (size_t)pos * 16 + 8) = hi;
    }
}

// ---------------- fused attention + beta gate + LN1 ----------------
// e-projection factored out algebraically:
//   score:  q·e = dot16(qwe, eattr) + qbe     (qwe = per-head q@We^T, computed in-wave)
//   output: sum_e wgt*e = (sum_e wgt*eattr)@We + l*be   (projected once per node)
__global__ __launch_bounds__(256, 3) void attn_kernel(
    const float* __restrict__ q, const unsigned int* __restrict__ kvb,
    const float* __restrict__ xr, const float* __restrict__ x,
    const unsigned short* __restrict__ eas, const int* __restrict__ srcs,
    const int* __restrict__ rs,
    const float* __restrict__ We, const float* __restrict__ be,
    const float* __restrict__ Wbeta,
    const float* __restrict__ gamma1, const float* __restrict__ beta1,
    float* __restrict__ hout, unsigned int* __restrict__ hbf)
{
    int wave = threadIdx.x >> 6;
    int lane = threadIdx.x & 63;
    int n = blockIdx.x * 4 + wave;
    if (n >= NN) return;
    int c0 = lane * 2, c1 = c0 + 1;
    int jlane = lane & 15;           // position within 16-lane head group
    int hbase = lane & 48;           // first lane of my head group

    // We columns for my two channels (node-independent)
    float we0[16], we1[16];
    #pragma unroll
    for (int j = 0; j < 16; j++) { we0[j] = We[j * 128 + c0]; we1[j] = We[j * 128 + c1]; }
    float be0 = be[c0], be1 = be[c1];

    float2 q2 = *(const float2*)(q + (size_t)n * 128 + c0);
    q2.x *= 0.17677669529663687f;    // 1/sqrt(32) folded into q (inherited by qwe/qbe)
    q2.y *= 0.17677669529663687f;

    // qbe = (q/sqrt32)·be over my head's 32 channels
    float qbe = q2.x * be0 + q2.y * be1;
    qbe += __shfl_xor(qbe, 1); qbe += __shfl_xor(qbe, 2);
    qbe += __shfl_xor(qbe, 4); qbe += __shfl_xor(qbe, 8);
    // qwe_lane = sum_c q_c * We[jlane][c] over my head's channels
    float qwe = 0.f;
    #pragma unroll
    for (int j = 0; j < 16; j++) {
        float u = q2.x * we0[j] + q2.y * we1[j];
        u += __shfl_xor(u, 1); u += __shfl_xor(u, 2);
        u += __shfl_xor(u, 4); u += __shfl_xor(u, 8);
        if (jlane == j) qwe = u;
    }

    float l = 0.f, a0 = 0.f, a1 = 0.f, s = 0.f;
    int beg = rs[n], end = rs[n + 1];

    int sr_c[8]; unsigned short e_c[8];
    #pragma unroll
    for (int j = 0; j < 8; j++) {
        int idx = min(beg + j, EE - 1);
        sr_c[j] = srcs[idx];
        e_c[j] = eas[(size_t)idx * 16 + jlane];
    }
    for (int g = beg; g < end; g += 8) {
        uint2 kvp[8];
        #pragma unroll
        for (int j = 0; j < 8; j++)
            kvp[j] = *(const uint2*)(kvb + (size_t)sr_c[j] * 128 + (lane << 1));
        int gn = g + 8;
        int sr_n[8]; unsigned short e_n[8];
        #pragma unroll
        for (int j = 0; j < 8; j++) {
            int idx = min(gn + j, EE - 1);
            sr_n[j] = srcs[idx];
            e_n[j] = eas[(size_t)idx * 16 + jlane];
        }
        int cnt = end - g;
        #pragma unroll
        for (int j = 0; j < 8; j++) {
            if (j < cnt) {
                float ea = bf2f(e_c[j]);
                unsigned int kx = kvp[j].x, ky = kvp[j].y;
                float k0 = __uint_as_float(kx << 16);
                float v0 = __uint_as_float(kx & 0xffff0000u);
                float k1 = __uint_as_float(ky << 16);
                float v1 = __uint_as_float(ky & 0xffff0000u);
                float part = fmaf(q2.x, k0, fmaf(q2.y, k1, qwe * ea));
                part += __shfl_xor(part, 1);
                part += __shfl_xor(part, 2);
                part += __shfl_xor(part, 4);
                part += __shfl_xor(part, 8);
                float wgt = __expf(part + qbe);
                l += wgt;
                a0 = fmaf(wgt, v0, a0);
                a1 = fmaf(wgt, v1, a1);
                s = fmaf(wgt, ea, s);
            }
        }
        #pragma unroll
        for (int j = 0; j < 8; j++) { sr_c[j] = sr_n[j]; e_c[j] = e_n[j]; }
    }

    // add e-contribution to output: (sum wgt*eattr)@We + l*be
    float eo0 = l * be0, eo1 = l * be1;
    #pragma unroll
    for (int j = 0; j < 16; j++) {
        float sj = __shfl(s, hbase + j);
        eo0 = fmaf(sj, we0[j], eo0);
        eo1 = fmaf(sj, we1[j], eo1);
    }
    a0 += eo0; a1 += eo1;

    float inv = l > 0.f ? 1.f / l : 0.f;
    float o0 = a0 * inv, o1 = a1 * inv;

    float wbo0 = Wbeta[c0],        wbo1 = Wbeta[c1];
    float wbx0 = Wbeta[128 + c0],  wbx1 = Wbeta[128 + c1];
    float wbd0 = Wbeta[256 + c0],  wbd1 = Wbeta[256 + c1];
    float2 xr2 = *(const float2*)(xr + (size_t)n * 128 + c0);
    float bl = o0 * wbo0 + o1 * wbo1 + xr2.x * wbx0 + xr2.y * wbx1
             + (o0 - xr2.x) * wbd0 + (o1 - xr2.y) * wbd1;
    #pragma unroll
    for (int off = 1; off < 64; off <<= 1) bl += __shfl_xor(bl, off);
    float beta = 1.f / (1.f + __expf(-bl));
    float xs0 = beta * xr2.x + (1.f - beta) * o0;
    float xs1 = beta * xr2.y + (1.f - beta) * o1;

    float2 xv = *(const float2*)(x + (size_t)n * 128 + c0);
    float t0 = xv.x + xs0, t1 = xv.y + xs1;
    float sm = t0 + t1;
    #pragma unroll
    for (int off = 1; off < 64; off <<= 1) sm += __shfl_xor(sm, off);
    float mu = sm * (1.f / 128.f);
    float d0 = t0 - mu, d1 = t1 - mu;
    float vv = d0 * d0 + d1 * d1;
    #pragma unroll
    for (int off = 1; off < 64; off <<= 1) vv += __shfl_xor(vv, off);
    float is = rsqrtf(vv * (1.f / 128.f) + 1e-5f);
    float h0 = d0 * is * gamma1[c0] + beta1[c0];
    float h1 = d1 * is * gamma1[c1] + beta1[c1];
    *(float2*)(hout + (size_t)n * 128 + c0) = make_float2(h0, h1);
    hbf[(size_t)n * 64 + lane] = (unsigned int)f2bf(h0) | ((unsigned int)f2bf(h1) << 16);
}

// ---------------- final LN over h + ff2 ----------------
__global__ __launch_bounds__(256) void ln2_k(
    const float* __restrict__ h, const float* __restrict__ ff2,
    const float* __restrict__ gamma2, const float* __restrict__ beta2,
    float* __restrict__ out)
{
    int wave = threadIdx.x >> 6;
    int lane = threadIdx.x & 63;
    int n = blockIdx.x * 4 + wave;
    if (n >= NN) return;
    int c0 = lane * 2;
    float2 hv = *(const float2*)(h + (size_t)n * 128 + c0);
    float2 fv = *(const float2*)(ff2 + (size_t)n * 128 + c0);
    float t0 = hv.x + fv.x, t1 = hv.y + fv.y;
    float sm = t0 + t1;
    #pragma unroll
    for (int off = 1; off < 64; off <<= 1) sm += __shfl_xor(sm, off);
    float mu = sm * (1.f / 128.f);
    float d0 = t0 - mu, d1 = t1 - mu;
    float vv = d0 * d0 + d1 * d1;
    #pragma unroll
    for (int off = 1; off < 64; off <<= 1) vv += __shfl_xor(vv, off);
    float is = rsqrtf(vv * (1.f / 128.f) + 1e-5f);
    float o0 = d0 * is * gamma2[c0] + beta2[c0];
    float o1 = d1 * is * gamma2[c0 + 1] + beta2[c0 + 1];
    *(float2*)(out + (size_t)n * 128 + c0) = make_float2(o0, o1);
}

extern "C" void kernel_launch(void* const* d_in, const int* in_sizes, int n_in,
                              void* d_out, int out_size, void* d_ws, size_t ws_size,
                              hipStream_t stream) {
    const float* x      = (const float*)d_in[0];
    const int*   eindex = (const int*)d_in[1];
    const float* eattr  = (const float*)d_in[2];
    const float* Wq = (const float*)d_in[3];  const float* bq = (const float*)d_in[4];
    const float* Wk = (const float*)d_in[5];  const float* bk = (const float*)d_in[6];
    const float* Wv = (const float*)d_in[7];  const float* bv = (const float*)d_in[8];
    const float* We = (const float*)d_in[9];  const float* be = (const float*)d_in[10];
    const float* Ws = (const float*)d_in[11]; const float* bs = (const float*)d_in[12];
    const float* Wbeta = (const float*)d_in[13];
    const float* g1 = (const float*)d_in[14]; const float* b1 = (const float*)d_in[15];
    const float* Wf1 = (const float*)d_in[16]; const float* bf1 = (const float*)d_in[17];
    const float* Wf2 = (const float*)d_in[18]; const float* bf2 = (const float*)d_in[19];
    const float* g2 = (const float*)d_in[20]; const float* b2 = (const float*)d_in[21];

    char* ws = (char*)d_ws;
    size_t off = 0;
    #define ALLOC(ptr, type, bytes) type* ptr = (type*)(ws + off); off = (off + (size_t)(bytes) + 255) & ~(size_t)255;
    ALLOC(wqkvsT, unsigned short, 512 * 128 * 2)
    ALLOC(wf1T,   unsigned short, 512 * 128 * 2)
    ALLOC(wf2T,   unsigned short, 128 * 512 * 2)
    ALLOC(biasq,  float,          512 * 4)
    ALLOC(qb,     float,          (size_t)NN * 128 * 4)     // 25.6 MB
    ALLOC(kvb,    unsigned short, (size_t)NN * 256 * 2)     // 25.6 MB (overlaid by ff1 w/ qb)
    ALLOC(xrb,    float,          (size_t)NN * 128 * 4)     // 25.6 MB (overlaid by ff2)
    ALLOC(h,      float,          (size_t)NN * 128 * 4)     // 25.6 MB
    ALLOC(hbf,    unsigned int,   (size_t)NN * 128 * 2)     // 12.8 MB
    ALLOC(deg,    int,            2 * NN * 4)               // deg[NN] + cursor[NN], one region
    ALLOC(row_start, int,         (NN + 1) * 4)
    ALLOC(bsum,   int,            1024)
    ALLOC(srcs_sorted, int,       (size_t)EE * 4)           // 3.2 MB
    ALLOC(eas,    unsigned short, (size_t)EE * 16 * 2)      // 25.6 MB
    #undef ALLOC
    // total ~145 MB — below the R2-proven footprint
    int* cursor = deg + NN;
    unsigned short* ff1 = (unsigned short*)qb;   // qb+kvb are contiguous (25.6MB is 256-aligned)
    float* ff2 = xrb;

    hipMemsetAsync(deg, 0, (size_t)2 * NN * 4, stream);

    pack_w<<<770, 256, 0, stream>>>(Wq, Wk, Wv, Ws, bq, bk, bv, bs, Wf1, Wf2,
                                    wqkvsT, wf1T, wf2T, biasq);

    // q|k|v|xr projections with split epilogue
    gemm_k<false, 2><<<391 * 8, 256, 0, stream>>>(x, wqkvsT, biasq, nullptr,
                                                  qb, kvb, xrb, NN, 512, 128);

    // CSR by dst + permuted src/eattr
    hist_k<<<3125, 256, 0, stream>>>(eindex + EE, deg);
    scan_phaseA<<<196, 256, 0, stream>>>(deg, row_start, bsum);
    scan_phaseB<<<1, 256, 0, stream>>>(bsum, 196);
    scan_phaseC<<<196, 256, 0, stream>>>(row_start, bsum);
    scatter_k<<<3125, 256, 0, stream>>>(eindex, eindex + EE, eattr, row_start,
                                        cursor, srcs_sorted, eas);

    // fused attention + beta gate + residual + LN1
    attn_kernel<<<12500, 256, 0, stream>>>(qb, (const unsigned int*)kvb, xrb, x,
                                           eas, srcs_sorted, row_start,
                                           We, be, Wbeta, g1, b1, h, hbf);

    // FFN (ff1 overlays qb/kvb; ff2 overlays xrb — both dead after attn)
    gemm_k<true, 1><<<391 * 8, 256, 0, stream>>>(hbf, wf1T, bf1, ff1,
                                                 nullptr, nullptr, nullptr, NN, 512, 128);
    gemm_k<true, 0><<<391 * 2, 256, 0, stream>>>(ff1, wf2T, bf2, ff2,
                                                 nullptr, nullptr, nullptr, NN, 128, 512);

    // final LN
    ln2_k<<<12500, 256, 0, stream>>>(h, ff2, g2, b2, (float*)d_out);
}